// Round 5
// baseline (522.699 us; speedup 1.0000x reference)
//
#include <hip/hip_runtime.h>

// ============================================================================
// 2-layer LSTM cell + FF head, B=32768, IN=64, H=256, OUT=768.
//
// R7 = R6 with X-intermediate round-trips eliminated:
//   - pack_w (serial, tiny ~2MB): weight repack ONLY (W1/W2/W3 bf16 n-major,
//     gate packed into col bits [5:4]; W3 mult third permuted for in-ni
//     softmax). ~4 us, launch-dominated.
//   - lstm1: A operand reg-staged directly from f32 inp (chunk 0) and
//     state1.out (chunks 1-4) with f2bf conversion during LDS staging
//     (swizzled ds_write dest). X1 buffer gone (-40MB traffic).
//   - lstm2: A chunks 0-3 via global_load_lds from X2L (bf16 out1 written by
//     lstm1), chunks 4-7 reg-staged from state2.out f32. X2-high gone
//     (-48MB traffic). No worker blocks needed.
//   - B operand always global_load_lds x16 from packed bf16 weights.
//
// R5: both-sides XOR chunk swizzle (stored chunk = global chunk ^ (row&7));
//     reg path swizzles ds_write dest, gl_lds path inverse-swizzles the
//     global source column. 16-way -> 8-way floor on fragment ds_read_b128.
// R4: m97 128x128 GEMM structure, register-only epilogues, XCD-aware remap.
//
// d_in order: 0 inp 1 state1 2 state2 | 3 l1_wf 4 l1_bf 5 l2_wf 6 l2_bf
//  7 l1_wk 8 l1_bk 9 l2_wk 10 l2_bk | 11 l1_wi 12 l1_bi 13 l2_wi 14 l2_bi
// 15 l1_ws 16 l1_bs 17 l2_ws 18 l2_bs | 19 ff_w[256,768]  (all f32)
//
// d_out (f32): means[B,256] | dev[B,256] | mult[B,256] | ns1[B,512] | ns2[B,512]
// ============================================================================

typedef __attribute__((ext_vector_type(8))) short short8;    // 8 bf16
typedef __attribute__((ext_vector_type(4))) short short4_t;  // 4 bf16 = 8 B
typedef __attribute__((ext_vector_type(4))) float floatx4;   // MFMA acc

#define BATCH 32768

static const size_t DEV_OFF  = (size_t)BATCH * 256;
static const size_t MULT_OFF = (size_t)2 * BATCH * 256;
static const size_t NS1_OFF  = (size_t)3 * BATCH * 256;
static const size_t NS2_OFF  = NS1_OFF + (size_t)BATCH * 512;

// workspace layout (ushort elements)
static const size_t W1P = 0;                                 // [1024][320]
static const size_t W2P = (size_t)1024 * 320;                // [1024][512]
static const size_t W3P = W2P + (size_t)1024 * 512;          // [768][256]
static const size_t X2L = W3P + (size_t)768 * 256;           // [B][256] out1 bf16
static const size_t X3O = X2L + (size_t)BATCH * 256;         // [B][256] out2 bf16

__device__ __forceinline__ unsigned short f2bf(float f) {
    union { float f; unsigned int i; } v; v.f = f;
    unsigned int i = v.i;
    i += 0x7fff + ((i >> 16) & 1);   // RNE
    return (unsigned short)(i >> 16);
}
__device__ __forceinline__ float sigmoidf_(float x) {
    return 1.f / (1.f + __expf(-x));
}
__device__ __forceinline__ float tanhf_(float x) {
    float e = __expf(2.f * x);       // inf-safe: x>>0 -> 1, x<<0 -> -1
    return 1.f - 2.f / (e + 1.f);
}

// async global->LDS, 16 B per lane; LDS dest = wave-uniform base + lane*16
__device__ __forceinline__ void gl_lds16(const unsigned short* g,
                                         unsigned short* l) {
    __builtin_amdgcn_global_load_lds(
        (const __attribute__((address_space(1))) unsigned int*)g,
        (__attribute__((address_space(3))) unsigned int*)l,
        16, 0, 0);
}

// ---------------------------------------------------------------------------
// pack_w: weights only. 262,144 quads = 1024 blocks x 256 thr x 1 quad.
//   [0,81920)        W1 [1024][320]  (c = (h>>4)*64 + g*16 + (h&15))
//   [81920,212992)   W2 [1024][512]  (same col mapping)
//   [212992,262144)  W3 [768][256]   (mult third: c = 512+(t>>4)*64+m*16+(t&15))
// ---------------------------------------------------------------------------
__global__ __launch_bounds__(256) void pack_w(
    const float* __restrict__ w10, const float* __restrict__ w11,
    const float* __restrict__ w12, const float* __restrict__ w13,
    const float* __restrict__ w20, const float* __restrict__ w21,
    const float* __restrict__ w22, const float* __restrict__ w23,
    const float* __restrict__ fw, unsigned short* __restrict__ ws)
{
    const int q = blockIdx.x * 256 + threadIdx.x;
    if (q < 81920) {
        int n = q / 80, k = (q % 80) << 2;
        int hh = ((n >> 6) << 4) + (n & 15);
        int g = (n >> 4) & 3;
        const float* s = g == 0 ? w10 : g == 1 ? w11 : g == 2 ? w12 : w13;
        short4_t o;
        o.x = (short)f2bf(s[(size_t)(k + 0) * 256 + hh]);
        o.y = (short)f2bf(s[(size_t)(k + 1) * 256 + hh]);
        o.z = (short)f2bf(s[(size_t)(k + 2) * 256 + hh]);
        o.w = (short)f2bf(s[(size_t)(k + 3) * 256 + hh]);
        *(short4_t*)(ws + W1P + (size_t)n * 320 + k) = o;
    } else if (q < 212992) {
        int j = q - 81920;
        int n = j >> 7, k = (j & 127) << 2;
        int hh = ((n >> 6) << 4) + (n & 15);
        int g = (n >> 4) & 3;
        const float* s = g == 0 ? w20 : g == 1 ? w21 : g == 2 ? w22 : w23;
        short4_t o;
        o.x = (short)f2bf(s[(size_t)(k + 0) * 256 + hh]);
        o.y = (short)f2bf(s[(size_t)(k + 1) * 256 + hh]);
        o.z = (short)f2bf(s[(size_t)(k + 2) * 256 + hh]);
        o.w = (short)f2bf(s[(size_t)(k + 3) * 256 + hh]);
        *(short4_t*)(ws + W2P + (size_t)n * 512 + k) = o;
    } else {
        int j = q - 212992;
        int n = j >> 6, k = (j & 63) << 2;
        int col;
        if (n < 512) col = n;                       // means | deviances
        else {                                      // mult third, partner-in-ni
            int t = (((n - 512) >> 6) << 4) + (n & 15);
            int m = (n >> 4) & 3;
            col = 512 + m * 64 + t;
        }
        short4_t o;
        o.x = (short)f2bf(fw[(size_t)(k + 0) * 768 + col]);
        o.y = (short)f2bf(fw[(size_t)(k + 1) * 768 + col]);
        o.z = (short)f2bf(fw[(size_t)(k + 2) * 768 + col]);
        o.w = (short)f2bf(fw[(size_t)(k + 3) * 768 + col]);
        *(short4_t*)(ws + W3P + (size_t)n * 256 + k) = o;
    }
}

// ---------------------------------------------------------------------------
// LSTM GEMM+cell: 128x128 tile, BK=64, 4 waves, XOR chunk swizzle,
// XCD-aware remap, register-only cell update.
// A staging:
//   L1 (KT=320): all chunks reg-staged f32->bf16 (c0: inp[B,64]; c1-4:
//                state.out cols (c-1)*64..)
//   L2 (KT=512): c0-3 gl_lds from xbf (X2L bf16); c4-7 reg-staged from
//                state.out f32.
// B staging: gl_lds x16 from packed weights (always).
// ---------------------------------------------------------------------------
template<int KT, bool L1>
__global__ __launch_bounds__(256, 4) void lstm_gemm(
    const float* __restrict__ f32x,           // L1: inp [B,64]; L2: unused
    const unsigned short* __restrict__ xbf,   // L2: X2L [B,256]; L1: unused
    const unsigned short* __restrict__ wp,    // [1024][KT] bf16 packed cols
    const float* __restrict__ b0, const float* __restrict__ b1,
    const float* __restrict__ b2, const float* __restrict__ b3,
    const float* __restrict__ state,          // [B][512] f32: out|cell
    float* __restrict__ nstate,               // [B][512] f32
    unsigned short* __restrict__ xnext)       // [B][256] bf16
{
    __shared__ __align__(16) struct {
        unsigned short a[128][64];
        unsigned short b[128][64];
    } lds;

    const int tid  = threadIdx.x;
    const int w    = tid >> 6;
    const int lane = tid & 63;
    const int lhi  = lane >> 4, llo = lane & 15;
    const int wr   = w >> 1, wc = w & 1;

    // XCD-aware remap: same A-tile consumed by 8 consecutive same-XCD blocks
    const int lin  = blockIdx.x;
    const int xcd  = lin & 7;
    const int kk   = lin >> 3;
    const int nt   = kk & 7;
    const int row0 = (xcd * 32 + (kk >> 3)) * 128;
    const int nc0  = nt * 128;

    // bias hoist (lane owns h = nt*32 + wc*16 + llo)
    const int h = nt * 32 + wc * 16 + llo;
    const float bf_ = b0[h], bk_ = b1[h], bi_ = b2[h], bs_ = b3[h];

    floatx4 acc[4][4];
#pragma unroll
    for (int i = 0; i < 4; i++)
#pragma unroll
        for (int j = 0; j < 4; j++) acc[i][j] = (floatx4){0.f, 0.f, 0.f, 0.f};

    // gl_lds staging geometry (B always; A for L2 low chunks)
    const int arow  = (w << 5) + (lane >> 3);     // wave stages 32 rows
    const int acolb = (((lane & 7) ^ ((lane >> 3) & 7)) << 3);  // ushort off
    const unsigned short* bgp = wp + (size_t)(nc0 + arow) * KT + acolb;
    const unsigned short* agp =
        L1 ? nullptr : xbf + (size_t)(row0 + arow) * 256 + acolb;

    // reg-stage geometry (A f32 chunks): thread covers rows r0+p*16, col c4
    const int r0  = tid >> 4;              // 0..15
    const int c4  = (tid & 15) << 2;       // f32 col within chunk
    const int chk = c4 >> 3;               // global 16B-chunk index (0..7)
    const int hlf = c4 & 7;                // 0 or 4 (ushort offset)

    // swizzled read chunk offsets (ushort): chunk = (ks*4+lhi) ^ (llo&7)
    const int sx  = llo & 7;
    const int kq0 = ((lhi ^ sx) << 3);
    const int kq1 = (((4 | lhi) ^ sx) << 3);

    for (int c = 0; c < KT / 64; ++c) {
        const int kb = c << 6;
        // --- B staging (gl_lds, pre-swizzled source col) ---
#pragma unroll
        for (int p = 0; p < 4; ++p)
            gl_lds16(bgp + (size_t)(p * 8) * KT + kb,
                     &lds.b[(w << 5) + (p << 3)][0]);
        // --- A staging ---
        if (!L1 && c < 4) {
#pragma unroll
            for (int p = 0; p < 4; ++p)
                gl_lds16(agp + (size_t)(p * 8) * 256 + kb,
                         &lds.a[(w << 5) + (p << 3)][0]);
        } else {
            const float* src; int sstr, scol;
            if (L1) {
                if (c == 0) { src = f32x;  sstr = 64;  scol = 0; }
                else        { src = state; sstr = 512; scol = (c - 1) * 64; }
            } else          { src = state; sstr = 512; scol = (c - 4) * 64; }
#pragma unroll
            for (int g2 = 0; g2 < 2; ++g2) {
                float4 v[4];
#pragma unroll
                for (int qq = 0; qq < 4; ++qq) {
                    const int r = r0 + (g2 * 4 + qq) * 16;
                    v[qq] = *(const float4*)(src + (size_t)(row0 + r) * sstr
                                             + scol + c4);
                }
#pragma unroll
                for (int qq = 0; qq < 4; ++qq) {
                    const int r = r0 + (g2 * 4 + qq) * 16;
                    short4_t hh;
                    hh.x = (short)f2bf(v[qq].x); hh.y = (short)f2bf(v[qq].y);
                    hh.z = (short)f2bf(v[qq].z); hh.w = (short)f2bf(v[qq].w);
                    // swizzled dest: stored chunk = chk ^ (r&7)
                    *(short4_t*)&lds.a[r][((chk ^ (r & 7)) << 3) + hlf] = hh;
                }
            }
        }
        __syncthreads();
        // --- compute: 2 k-steps of 32 ---
#pragma unroll
        for (int ks = 0; ks < 2; ++ks) {
            const int kq = ks ? kq1 : kq0;
            short8 a[4], b[4];
#pragma unroll
            for (int mi = 0; mi < 4; mi++)
                a[mi] = *(const short8*)&lds.a[wr * 64 + mi * 16 + llo][kq];
#pragma unroll
            for (int ni = 0; ni < 4; ni++)
                b[ni] = *(const short8*)&lds.b[wc * 64 + ni * 16 + llo][kq];
#pragma unroll
            for (int mi = 0; mi < 4; mi++)
#pragma unroll
                for (int ni = 0; ni < 4; ni++)
                    acc[mi][ni] = __builtin_amdgcn_mfma_f32_16x16x32_bf16(
                        a[mi], b[ni], acc[mi][ni], 0, 0, 0);
        }
        __syncthreads();
    }

    // ---- register-only cell update ----
#pragma unroll
    for (int mi = 0; mi < 4; mi++)
#pragma unroll
        for (int r = 0; r < 4; r++) {
            const int m = wr * 64 + mi * 16 + lhi * 4 + r;
            const size_t rowel = (size_t)(row0 + m) * 512;
            float rst = sigmoidf_(acc[mi][0][r] + bf_);
            float wrt = sigmoidf_(acc[mi][1][r] + bk_);
            float itm = tanhf_(acc[mi][2][r] + bi_);
            float rd  = sigmoidf_(acc[mi][3][r] + bs_);
            float cold = state[rowel + 256 + h];
            float cell = rst * cold + wrt * itm;
            float o = rd * tanhf_(cell);
            nstate[rowel + h]       = o;
            nstate[rowel + 256 + h] = cell;
            xnext[(size_t)(row0 + m) * 256 + h] = f2bf(o);
        }
}

// ---------------------------------------------------------------------------
// FF head GEMM: X3[B,256] @ W3p[768,256]; grid 1536 1D, XCD-remapped,
// XOR chunk swizzle.  nt 0,1 -> means; nt 2,3 -> exp(dev);
// nt 4,5 -> mult (softmax partners in ni dimension, register-only).
// ---------------------------------------------------------------------------
__global__ __launch_bounds__(256, 4) void ff_gemm(
    const unsigned short* __restrict__ xin,   // [B][256] bf16
    const unsigned short* __restrict__ wp,    // [768][256] bf16 packed
    float* __restrict__ out)
{
    __shared__ __align__(16) struct {
        unsigned short a[128][64];
        unsigned short b[128][64];
    } lds;

    const int tid  = threadIdx.x;
    const int w    = tid >> 6;
    const int lane = tid & 63;
    const int lhi  = lane >> 4, llo = lane & 15;
    const int wr   = w >> 1, wc = w & 1;

    const int lin  = blockIdx.x;
    const int xcd  = lin & 7;
    const int kk   = lin >> 3;                // [0,192)
    const int nt   = kk % 6;
    const int row0 = (xcd * 32 + kk / 6) * 128;
    const int nc0  = nt * 128;

    floatx4 acc[4][4];
#pragma unroll
    for (int i = 0; i < 4; i++)
#pragma unroll
        for (int j = 0; j < 4; j++) acc[i][j] = (floatx4){0.f, 0.f, 0.f, 0.f};

    const int arow  = (w << 5) + (lane >> 3);
    const int acolb = (((lane & 7) ^ ((lane >> 3) & 7)) << 3);
    const unsigned short* agp = xin + (size_t)(row0 + arow) * 256 + acolb;
    const unsigned short* bgp = wp  + (size_t)(nc0 + arow) * 256 + acolb;

    const int sx  = llo & 7;
    const int kq0 = ((lhi ^ sx) << 3);
    const int kq1 = (((4 | lhi) ^ sx) << 3);

    for (int c = 0; c < 4; ++c) {
        const int kb = c << 6;
#pragma unroll
        for (int p = 0; p < 4; ++p) {
            gl_lds16(agp + (size_t)(p * 8) * 256 + kb,
                     &lds.a[(w << 5) + (p << 3)][0]);
            gl_lds16(bgp + (size_t)(p * 8) * 256 + kb,
                     &lds.b[(w << 5) + (p << 3)][0]);
        }
        __syncthreads();
#pragma unroll
        for (int ks = 0; ks < 2; ++ks) {
            const int kq = ks ? kq1 : kq0;
            short8 a[4], b[4];
#pragma unroll
            for (int mi = 0; mi < 4; mi++)
                a[mi] = *(const short8*)&lds.a[wr * 64 + mi * 16 + llo][kq];
#pragma unroll
            for (int ni = 0; ni < 4; ni++)
                b[ni] = *(const short8*)&lds.b[wc * 64 + ni * 16 + llo][kq];
#pragma unroll
            for (int mi = 0; mi < 4; mi++)
#pragma unroll
                for (int ni = 0; ni < 4; ni++)
                    acc[mi][ni] = __builtin_amdgcn_mfma_f32_16x16x32_bf16(
                        a[mi], b[ni], acc[mi][ni], 0, 0, 0);
        }
        __syncthreads();
    }

    if (nt < 4) {
        const bool dev = (nt >= 2);
        float* obase = out + (dev ? DEV_OFF : (size_t)0);
        const int cb = (nt & 1) * 128 + wc * 64;
#pragma unroll
        for (int mi = 0; mi < 4; mi++)
#pragma unroll
            for (int ni = 0; ni < 4; ni++) {
                const int cc = cb + ni * 16 + llo;
#pragma unroll
                for (int r = 0; r < 4; r++) {
                    const int m = wr * 64 + mi * 16 + lhi * 4 + r;
                    float v = acc[mi][ni][r];
                    if (dev) v = __expf(v);
                    obase[(size_t)(row0 + m) * 256 + cc] = v;
                }
            }
    } else {
        // mult: lane owns t = (nt-4)*32 + wc*16 + llo; partners in ni
        const int t = (nt - 4) * 32 + wc * 16 + llo;
#pragma unroll
        for (int mi = 0; mi < 4; mi++)
#pragma unroll
            for (int r = 0; r < 4; r++) {
                const int mrow = wr * 64 + mi * 16 + lhi * 4 + r;
                float v0 = acc[mi][0][r], v1 = acc[mi][1][r];
                float v2 = acc[mi][2][r], v3 = acc[mi][3][r];
                float mx = fmaxf(fmaxf(v0, v1), fmaxf(v2, v3));
                float e0 = __expf(v0 - mx), e1 = __expf(v1 - mx);
                float e2 = __expf(v2 - mx), e3 = __expf(v3 - mx);
                float inv = 1.f / (e0 + e1 + e2 + e3);
                size_t base = MULT_OFF + (size_t)(row0 + mrow) * 256 + t;
                out[base]       = e0 * inv;
                out[base + 64]  = e1 * inv;
                out[base + 128] = e2 * inv;
                out[base + 192] = e3 * inv;
            }
    }
}

// ---------------------------------------------------------------------------
extern "C" void kernel_launch(void* const* d_in, const int* in_sizes, int n_in,
                              void* d_out, int out_size, void* d_ws, size_t ws_size,
                              hipStream_t stream)
{
    typedef const float* cfp;
    cfp inp = (cfp)d_in[0];
    cfp st1 = (cfp)d_in[1];
    cfp st2 = (cfp)d_in[2];
    cfp l1w0 = (cfp)d_in[3],  l1w1 = (cfp)d_in[7],  l1w2 = (cfp)d_in[11], l1w3 = (cfp)d_in[15];
    cfp l1b0 = (cfp)d_in[4],  l1b1 = (cfp)d_in[8],  l1b2 = (cfp)d_in[12], l1b3 = (cfp)d_in[16];
    cfp l2w0 = (cfp)d_in[5],  l2w1 = (cfp)d_in[9],  l2w2 = (cfp)d_in[13], l2w3 = (cfp)d_in[17];
    cfp l2b0 = (cfp)d_in[6],  l2b1 = (cfp)d_in[10], l2b2 = (cfp)d_in[14], l2b3 = (cfp)d_in[18];
    cfp ffw = (cfp)d_in[19];

    float* out = (float*)d_out;
    unsigned short* ws = (unsigned short*)d_ws;

    // weights-only repack: 262,144 quads = 1024 blocks
    pack_w<<<1024, 256, 0, stream>>>(l1w0, l1w1, l1w2, l1w3,
                                     l2w0, l2w1, l2w2, l2w3, ffw, ws);

    // layer 1: A = [inp | s1.out] reg-staged f32->bf16; out1 bf16 -> X2L
    lstm_gemm<320, true><<<2048, 256, 0, stream>>>(
        inp, nullptr, ws + W1P, l1b0, l1b1, l1b2, l1b3,
        st1, out + NS1_OFF, ws + X2L);

    // layer 2: A low = X2L bf16 (gl_lds), high = s2.out f32 reg-staged
    lstm_gemm<512, false><<<2048, 256, 0, stream>>>(
        nullptr, ws + X2L, ws + W2P, l2b0, l2b1, l2b2, l2b3,
        st2, out + NS2_OFF, ws + X3O);

    // FF head + fused epilogues
    ff_gemm<<<1536, 256, 0, stream>>>(ws + X3O, ws + W3P, out);
}